// Round 15
// baseline (7625.652 us; speedup 1.0000x reference)
//
#include <hip/hip_runtime.h>
#include <math.h>

#define LSEQ 128
#define BATCH 64
#define EDIM 512
#define HDIM 1024
#define N3 3072
#define NWG 256
#define NTH 1024
#define GXT ((size_t)(N3 * BATCH))   // floats per time step in gxT ([3072][64])
#define BARSTRIDE 768                // ints per barrier instance

typedef float v4f __attribute__((ext_vector_type(4)));

// ---------------------------------------------------------------------------
// agent-scope (IF-serviced, cross-XCD coherent) 16B accesses
// ---------------------------------------------------------------------------
__device__ __forceinline__ v4f sc1Ld4(const float* p) {
    v4f v;
    asm volatile("global_load_dwordx4 %0, %1, off sc1"
                 : "=v"(v) : "v"(p) : "memory");
    return v;
}
__device__ __forceinline__ void sc1St4(float* p, v4f v) {
    asm volatile("global_store_dwordx4 %0, %1, off sc1"
                 : : "v"(p), "v"(v) : "memory");
}

// ---------------------------------------------------------------------------
// XCD-local atomic (serviced at the issuing XCD's L2; no sc1 -> not IF-routed).
// Atomics always execute at L2 (never satisfied from L1), so add-0 is a safe
// L2-visible read. sc0 = return-old.
// ---------------------------------------------------------------------------
__device__ __forceinline__ int l2AtomicAdd(int* p, int v) {
    int old;
    asm volatile("global_atomic_add %0, %1, %2, off sc0\n\ts_waitcnt vmcnt(0)"
                 : "=v"(old) : "v"(p), "v"(v) : "memory");
    return old;
}
__device__ __forceinline__ int xccId() {
    int x;
    asm("s_getreg_b32 %0, hwreg(HW_REG_XCC_ID)" : "=s"(x));
    return x & 7;
}

// ---------------------------------------------------------------------------
// Hierarchical grid barrier (v11's, proven). Layout per instance (pre-zeroed):
//   arr[x] at x*32 | root at 256 | rootrel at 288 | rel[x] at (16+x)*32
// Local arrivals in parallel across 8 L2s; ~9 agent-scope ops per barrier.
// Local pollers use atomic add-0 (L2-executed, never L1-stale) with an
// agent-scope fallback check every 64 sleeps.
// ---------------------------------------------------------------------------
__device__ __forceinline__ void xcd_bar(int* base, int myx, int cntx, int nxcd) {
    __syncthreads();
    if (threadIdx.x == 0) {
        asm volatile("s_waitcnt vmcnt(0)" ::: "memory");
        const int old = l2AtomicAdd(&base[myx * 32], 1);
        if (old == cntx - 1) {
            const int rold = __hip_atomic_fetch_add(&base[256], 1,
                                 __ATOMIC_RELAXED, __HIP_MEMORY_SCOPE_AGENT);
            if (rold == nxcd - 1)
                __hip_atomic_store(&base[288], 1, __ATOMIC_RELAXED,
                                   __HIP_MEMORY_SCOPE_AGENT);
            while (__hip_atomic_load(&base[288], __ATOMIC_RELAXED,
                                     __HIP_MEMORY_SCOPE_AGENT) == 0)
                __builtin_amdgcn_s_sleep(1);
            l2AtomicAdd(&base[(16 + myx) * 32], 1);
        } else {
            int it = 0;
            while (l2AtomicAdd(&base[(16 + myx) * 32], 0) == 0) {
                __builtin_amdgcn_s_sleep(1);
                if ((++it & 63) == 0) {
                    if (__hip_atomic_load(&base[288], __ATOMIC_RELAXED,
                                          __HIP_MEMORY_SCOPE_AGENT) != 0)
                        break;
                }
            }
        }
    }
    __syncthreads();
}

// ---------------------------------------------------------------------------
// f32 tiled GEMM, optional row-gather on A. Output BLOCK-TRANSPOSED to gxT.
// ---------------------------------------------------------------------------
__global__ __launch_bounds__(256) void gemm_biasT(
    const float* __restrict__ A, const int* __restrict__ idx, int K,
    const float* __restrict__ Bm, const float* __restrict__ bias,
    float* __restrict__ C, int N)
{
    __shared__ float Sm[4352];
    float* As = Sm;
    float* Bs = Sm + 2176;
    const int tid = threadIdx.x;
    const int m0 = blockIdx.y * 64, n0 = blockIdx.x * 64;
    const int ty = tid >> 4, tx = tid & 15;

    float acc[4][4] = {};

    const int ra = tid >> 3;
    const int kq = (tid & 7) << 2;
    const int kb = tid >> 4;
    const int nq = (tid & 15) << 2;

    for (int k0 = 0; k0 < K; k0 += 32) {
        #pragma unroll
        for (int h2 = 0; h2 < 2; ++h2) {
            const int row = ra + h2 * 32;
            const int grow = idx ? idx[m0 + row] : (m0 + row);
            const float4 v = *reinterpret_cast<const float4*>(&A[(size_t)grow * K + k0 + kq]);
            As[(kq + 0) * 68 + row] = v.x; As[(kq + 1) * 68 + row] = v.y;
            As[(kq + 2) * 68 + row] = v.z; As[(kq + 3) * 68 + row] = v.w;
        }
        #pragma unroll
        for (int h2 = 0; h2 < 2; ++h2) {
            const int kk = kb + h2 * 16;
            *reinterpret_cast<float4*>(&Bs[kk * 68 + nq]) =
                *reinterpret_cast<const float4*>(&Bm[(size_t)(k0 + kk) * N + n0 + nq]);
        }
        __syncthreads();
        #pragma unroll
        for (int k = 0; k < 32; ++k) {
            const float4 a4 = *reinterpret_cast<const float4*>(&As[k * 68 + ty * 4]);
            const float4 b4 = *reinterpret_cast<const float4*>(&Bs[k * 68 + tx * 4]);
            const float av[4] = {a4.x, a4.y, a4.z, a4.w};
            const float bv[4] = {b4.x, b4.y, b4.z, b4.w};
            #pragma unroll
            for (int i = 0; i < 4; ++i)
                #pragma unroll
                for (int j = 0; j < 4; ++j)
                    acc[i][j] += av[i] * bv[j];
        }
        __syncthreads();
    }

    #pragma unroll
    for (int i = 0; i < 4; ++i) {
        float4 v = {acc[i][0] + bias[n0 + tx * 4 + 0],
                    acc[i][1] + bias[n0 + tx * 4 + 1],
                    acc[i][2] + bias[n0 + tx * 4 + 2],
                    acc[i][3] + bias[n0 + tx * 4 + 3]};
        *reinterpret_cast<float4*>(&Sm[(ty * 4 + i) * 65 + tx * 4]) = v;
    }
    __syncthreads();
    const int mloc = tid & 63, nq2 = tid >> 6;
    const size_t base = (size_t)blockIdx.y * ((size_t)N * 64) + (size_t)n0 * 64;
    #pragma unroll
    for (int q = 0; q < 16; ++q) {
        const int nl = nq2 * 16 + q;
        C[base + (size_t)nl * 64 + mloc] = Sm[mloc * 65 + nl];
    }
}

// ---------------------------------------------------------------------------
// GRU scan v14 — v11 structure with 2-chain ILP GEMMs (16 wave-loads in
// flight vs 8: halves the structural cold-miss latency of the h/rh reads).
// Zone-overlay invariants (unchanged since v6):
//   h(t)  -> zone(u)[c][b], rh(t) -> zone(u)[1024+c][b], u = t-1 fwd / t+1 bwd
//   zone(x) = gxT + x*GXT for 0<=x<L else scr (per-direction).
// Gate z/r regions only ever read via sc1; overlay data plain-read only at
// fresh addresses after a barrier; cand region never overlaid.
// pre arena (pre-zeroed): [0] census counter, [16..23] per-XCD WG counts.
// ---------------------------------------------------------------------------
__global__ __launch_bounds__(NTH) void gru_scan14(
    float* __restrict__ gxT,
    float* __restrict__ scr,
    const float* __restrict__ Whzr,   // [1024][2048]
    const float* __restrict__ bhzr,
    const float* __restrict__ Whh,    // [1024][1024]
    const float* __restrict__ bhh,
    const float* __restrict__ mask,   // [L][B]
    float* __restrict__ out,          // [L][B][1024]
    int* __restrict__ bar,            // [2*LSEQ][BARSTRIDE] pre-zeroed
    int* __restrict__ pre,            // [32] pre-zeroed census arena
    int reverse)
{
    __shared__ float Wzr_l[HDIM * 16];   // [k][8z|8r]  64KB
    __shared__ float Whh_l[HDIM * 8];    // [k][8c]     32KB
    __shared__ float part[8192];         // 32KB reduce scratch
    __shared__ float gl[512];            // [16 gate cols][32b]
    __shared__ float candl[256];         // [8c][32b]
    __shared__ float zl[256];            // [8c][32b]
    __shared__ float hold[256];          // [8c][32b]
    __shared__ float rhl[256];           // [8c][32b]
    __shared__ float hl[256];            // [8c][32b]
    __shared__ float ml[32];

    const int wg = blockIdx.x, tid = threadIdx.x;
    const int w = tid >> 6, lane = tid & 63;
    const int bq = lane & 7, gp = lane >> 3;
    const int c0 = (wg >> 1) * 8;
    const int grp = wg & 1;
    const int b0 = grp * 32;

    const int myx = xccId();

    // ---- census: per-XCD membership counts (once) ----
    if (tid == 0)
        __hip_atomic_fetch_add(&pre[16 + myx], 1,
                               __ATOMIC_RELAXED, __HIP_MEMORY_SCOPE_AGENT);

    // one-time weight staging (k = tid)
    {
        const int k = tid;
        *(v4f*)&Wzr_l[k * 16]      = *(const v4f*)&Whzr[(size_t)k * 2048 + c0];
        *(v4f*)&Wzr_l[k * 16 + 4]  = *(const v4f*)&Whzr[(size_t)k * 2048 + c0 + 4];
        *(v4f*)&Wzr_l[k * 16 + 8]  = *(const v4f*)&Whzr[(size_t)k * 2048 + 1024 + c0];
        *(v4f*)&Wzr_l[k * 16 + 12] = *(const v4f*)&Whzr[(size_t)k * 2048 + 1024 + c0 + 4];
        *(v4f*)&Whh_l[k * 8]       = *(const v4f*)&Whh[(size_t)k * 1024 + c0];
        *(v4f*)&Whh_l[k * 8 + 4]   = *(const v4f*)&Whh[(size_t)k * 1024 + c0 + 4];
    }

    // ---- census barrier (flat, once) + count readback (leader only) ----
    int cntx = NWG, nxcd = 1;
    __syncthreads();
    if (tid == 0) {
        asm volatile("s_waitcnt vmcnt(0)" ::: "memory");
        __hip_atomic_fetch_add(&pre[0], 1, __ATOMIC_RELAXED,
                               __HIP_MEMORY_SCOPE_AGENT);
        while (__hip_atomic_load(&pre[0], __ATOMIC_RELAXED,
                                 __HIP_MEMORY_SCOPE_AGENT) < NWG)
            __builtin_amdgcn_s_sleep(2);
        nxcd = 0;
        for (int x2 = 0; x2 < 8; ++x2) {
            const int c = __hip_atomic_load(&pre[16 + x2], __ATOMIC_RELAXED,
                                            __HIP_MEMORY_SCOPE_AGENT);
            if (x2 == myx) cntx = c;
            if (c > 0) ++nxcd;
        }
    }
    __syncthreads();

    // reduce-A mapping (tid < 512): output (gate gcA, batch bA)
    const int remA = tid & 255;
    const int lqA = remA >> 2, eA = remA & 3;
    const int bA  = (lqA & 7) * 4 + ((tid >> 8) & 1) * 2 + (eA >> 1);
    const int gcA = (lqA >> 3) * 2 + (eA & 1);
    const int colA = (gcA < 8) ? (c0 + gcA) : (1024 + c0 + gcA - 8);
    const float bzrA = bhzr[colA & 2047];
    const int jA = gcA - 8;
    // reduce-B mapping (tid < 256): output (col cB, batch bB)
    const int lqB = tid >> 2, eB = tid & 3;
    const int bB = (lqB & 7) * 4 + eB;
    const int cB = lqB >> 3;
    const float bhhB = (tid < 256) ? bhh[c0 + cB] : 0.f;

    for (int s = 0; s < LSEQ; ++s) {
        const int t  = reverse ? (LSEQ - 1 - s) : s;
        const int u  = reverse ? (t + 1) : (t - 1);
        const int up = reverse ? (t + 2) : (t - 2);
        float* zoneU = (u >= 0 && u < LSEQ) ? (gxT + (size_t)u * GXT) : scr;
        const float* zoneP = (up >= 0 && up < LSEQ) ? (gxT + (size_t)up * GXT) : scr;
        int* barA = bar + (size_t)(2 * s) * BARSTRIDE;
        int* barB = bar + (size_t)(2 * s + 1) * BARSTRIDE;

        // ================= prefetch block (wave-role parallel) =================
        v4f gv = {0,0,0,0};
        float4 hv = {0,0,0,0}, cv = {0,0,0,0}, mv = {0,0,0,0};
        if (tid < 128) {                 // waves 0-1: z/r gates via sc1 x4
            const int ci = tid >> 3, qq = tid & 7;
            const int col = (ci < 8) ? (c0 + ci) : (1024 + c0 + ci - 8);
            gv = sc1Ld4(&gxT[(size_t)t * GXT + (size_t)col * 64 + b0 + qq * 4]);
        } else if (tid < 192) {          // wave 2: h_old own cols (plain, fresh)
            if (s > 0) {
                const int ci = (tid - 128) >> 3, qq = tid & 7;
                hv = *(const float4*)&zoneP[(size_t)(c0 + ci) * 64 + b0 + qq * 4];
            }
        } else if (tid < 256) {          // wave 3: cand gates (plain, never overlaid)
            const int ci = (tid - 192) >> 3, qq = tid & 7;
            cv = *(const float4*)&gxT[(size_t)t * GXT + (size_t)(2048 + c0 + ci) * 64 + b0 + qq * 4];
        } else if (tid < 264) {          // wave 4 lanes 0-7: mask
            const int qq = tid - 256;
            mv = *(const float4*)&mask[t * BATCH + b0 + qq * 4];
        }

        // ---- phase A GEMM: 2-chain ILP over K-slice [64w, 64w+64) ----
        float2 a00 = {0,0}, a01 = {0,0}, a10 = {0,0}, a11 = {0,0};
        float2 d00 = {0,0}, d01 = {0,0}, d10 = {0,0}, d11 = {0,0};
        if (s > 0) {
            const float* hb = zoneP + (size_t)(w * 64) * 64 + b0 + bq * 4;
            const float* wb = &Wzr_l[(w * 64) * 16 + gp * 2];
            #pragma unroll 8
            for (int kk = 0; kk < 32; ++kk) {
                const float4 h4 = *(const float4*)(hb + (size_t)kk * 64);
                const float4 g4 = *(const float4*)(hb + (size_t)(kk + 32) * 64);
                const float2 w2 = *(const float2*)(wb + kk * 16);
                const float2 v2 = *(const float2*)(wb + (kk + 32) * 16);
                a00.x += h4.x * w2.x; a00.y += h4.y * w2.x;
                a01.x += h4.z * w2.x; a01.y += h4.w * w2.x;
                a10.x += h4.x * w2.y; a10.y += h4.y * w2.y;
                a11.x += h4.z * w2.y; a11.y += h4.w * w2.y;
                d00.x += g4.x * v2.x; d00.y += g4.y * v2.x;
                d01.x += g4.z * v2.x; d01.y += g4.w * v2.x;
                d10.x += g4.x * v2.y; d10.y += g4.y * v2.y;
                d11.x += g4.z * v2.y; d11.y += g4.w * v2.y;
            }
            a00.x += d00.x; a00.y += d00.y; a01.x += d01.x; a01.y += d01.y;
            a10.x += d10.x; a10.y += d10.y; a11.x += d11.x; a11.y += d11.y;
        }
        asm volatile("s_waitcnt vmcnt(0)" ::: "memory");
        __builtin_amdgcn_sched_barrier(0);
        if (tid < 128) {
            *(v4f*)&gl[(tid >> 3) * 32 + (tid & 7) * 4] = gv;
        } else if (tid < 192) {
            *(float4*)&hold[((tid - 128) >> 3) * 32 + (tid & 7) * 4] = hv;
        } else if (tid < 256) {
            *(float4*)&candl[((tid - 192) >> 3) * 32 + (tid & 7) * 4] = cv;
        } else if (tid < 264) {
            *(float4*)&ml[(tid - 256) * 4] = mv;
        }
        {
            const float4 p0 = {a00.x, a10.x, a00.y, a10.y};
            const float4 p1 = {a01.x, a11.x, a01.y, a11.y};
            *(float4*)&part[w * 512 + lane * 4]       = p0;
            *(float4*)&part[w * 512 + 256 + lane * 4] = p1;
        }
        __syncthreads();
        if (tid < 512) {
            float sum = 0.f;
            #pragma unroll
            for (int ww = 0; ww < 16; ++ww) sum += part[ww * 512 + tid];
            const float pre_ = sum + bzrA + gl[gcA * 32 + bA];
            const float sig = 1.f / (1.f + expf(-pre_));
            if (gcA < 8) zl[gcA * 32 + bA] = sig;
            else         rhl[jA * 32 + bA] = sig * hold[jA * 32 + bA];
        }
        __syncthreads();
        if (tid < 64) {                  // 64 x4 sc1 stores: rh -> zoneU r-region
            const int ci = tid >> 3, qq = tid & 7;
            sc1St4(&zoneU[(size_t)(1024 + c0 + ci) * 64 + b0 + qq * 4],
                   *(const v4f*)&rhl[ci * 32 + qq * 4]);
        }
        xcd_bar(barA, myx, cntx, nxcd);

        // ---- phase B GEMM: 2-chain ILP over rh (plain b128, fresh) ----
        float2 q01 = {0,0}, q23 = {0,0}, r01 = {0,0}, r23 = {0,0};
        if (s > 0) {
            const float* rb  = zoneU + (size_t)(1024 + w * 64) * 64 + b0 + bq * 4;
            const float* wb2 = &Whh_l[(w * 64) * 8 + gp];
            #pragma unroll 8
            for (int kk = 0; kk < 32; ++kk) {
                const float4 r4 = *(const float4*)(rb + (size_t)kk * 64);
                const float4 s4 = *(const float4*)(rb + (size_t)(kk + 32) * 64);
                const float wv = wb2[kk * 8];
                const float xv = wb2[(kk + 32) * 8];
                q01.x += r4.x * wv; q01.y += r4.y * wv;
                q23.x += r4.z * wv; q23.y += r4.w * wv;
                r01.x += s4.x * xv; r01.y += s4.y * xv;
                r23.x += s4.z * xv; r23.y += s4.w * xv;
            }
            q01.x += r01.x; q01.y += r01.y; q23.x += r23.x; q23.y += r23.y;
        }
        {
            const float4 pv = {q01.x, q01.y, q23.x, q23.y};
            *(float4*)&part[w * 256 + lane * 4] = pv;
        }
        __syncthreads();
        if (tid < 256) {
            float sum = 0.f;
            #pragma unroll
            for (int ww = 0; ww < 16; ++ww) sum += part[ww * 256 + tid];
            const float pre_ = sum + bhhB + candl[cB * 32 + bB];
            const float hc = tanhf(pre_);
            const float z  = zl[cB * 32 + bB];
            const float ho = hold[cB * 32 + bB];
            float hn = ho + z * (hc - ho);
            hn = ho + ml[bB] * (hn - ho);
            hl[cB * 32 + bB] = hn;
        }
        __syncthreads();
        if (tid < 64) {                  // 64 x4 sc1 stores: h -> zoneU z-region
            const int ci = tid >> 3, qq = tid & 7;
            sc1St4(&zoneU[(size_t)(c0 + ci) * 64 + b0 + qq * 4],
                   *(const v4f*)&hl[ci * 32 + qq * 4]);
        } else if (tid < 128) {          // out[t][b][c0..c0+8) plain x4 stores
            const int e = tid - 64;
            const int b = e >> 1, half = e & 1;
            float4 v;
            v.x = hl[(half * 4 + 0) * 32 + b];
            v.y = hl[(half * 4 + 1) * 32 + b];
            v.z = hl[(half * 4 + 2) * 32 + b];
            v.w = hl[(half * 4 + 3) * 32 + b];
            *(float4*)&out[((size_t)t * BATCH + b0 + b) * HDIM + c0 + half * 4] = v;
        }
        xcd_bar(barB, myx, cntx, nxcd);
    }
}

// ---------------------------------------------------------------------------
extern "C" void kernel_launch(void* const* d_in, const int* in_sizes, int n_in,
                              void* d_out, int out_size, void* d_ws, size_t ws_size,
                              hipStream_t stream) {
    const int*   xs      = (const int*)  d_in[0];
    const float* xs_mask = (const float*)d_in[1];
    const float* emb     = (const float*)d_in[2];
    const float* fw_Wx   = (const float*)d_in[3];
    const float* fw_bx   = (const float*)d_in[4];
    const float* fw_Whzr = (const float*)d_in[5];
    const float* fw_bhzr = (const float*)d_in[6];
    const float* fw_Whh  = (const float*)d_in[7];
    const float* fw_bhh  = (const float*)d_in[8];
    const float* bw_Wx   = (const float*)d_in[9];
    const float* bw_bx   = (const float*)d_in[10];
    const float* bw_Whzr = (const float*)d_in[11];
    const float* bw_bhzr = (const float*)d_in[12];
    const float* bw_Whh  = (const float*)d_in[13];
    const float* bw_bhh  = (const float*)d_in[14];
    float* outp = (float*)d_out;

    const size_t BARN = (size_t)(2 * LSEQ) * BARSTRIDE;

    char* wp = (char*)d_ws;
    float* gxbuf = (float*)wp; wp += (size_t)LSEQ * GXT * sizeof(float);   // 100.7 MB
    float* scrF  = (float*)wp; wp += GXT * sizeof(float);
    float* scrB  = (float*)wp; wp += GXT * sizeof(float);
    int* barF    = (int*)wp;   wp += BARN * sizeof(int);
    int* barB    = (int*)wp;   wp += BARN * sizeof(int);
    int* preF    = (int*)wp;   wp += 32 * sizeof(int);
    int* preB    = (int*)wp;   wp += 32 * sizeof(int);

    hipMemsetAsync(barF, 0, (2 * BARN + 64) * sizeof(int), stream);

    const dim3 gemm_grid(N3 / 64, (LSEQ * BATCH) / 64);
    const dim3 gemm_blk(256);

    // ---- forward: gxT = (emb[xs] @ fw_Wx + fw_bx)^T-per-step ; scan ----
    hipLaunchKernelGGL(gemm_biasT, gemm_grid, gemm_blk, 0, stream,
                       emb, xs, EDIM, fw_Wx, fw_bx, gxbuf, N3);
    {
        int rev = 0;
        void* args[] = {(void*)&gxbuf, (void*)&scrF, (void*)&fw_Whzr, (void*)&fw_bhzr,
                        (void*)&fw_Whh, (void*)&fw_bhh, (void*)&xs_mask,
                        (void*)&outp, (void*)&barF, (void*)&preF, (void*)&rev};
        (void)hipLaunchCooperativeKernel((const void*)gru_scan14, dim3(NWG), dim3(NTH),
                                         args, 0, stream);
    }

    // ---- backward: gxT = (right @ bw_Wx + bw_bx)^T-per-step ; scan ----
    {
        const float* rightp = (const float*)d_out;
        const int* noidx = nullptr;
        hipLaunchKernelGGL(gemm_biasT, gemm_grid, gemm_blk, 0, stream,
                           rightp, noidx, HDIM, bw_Wx, bw_bx, gxbuf, N3);
    }
    {
        int rev = 1;
        void* args[] = {(void*)&gxbuf, (void*)&scrB, (void*)&bw_Whzr, (void*)&bw_bhzr,
                        (void*)&bw_Whh, (void*)&bw_bhh, (void*)&xs_mask,
                        (void*)&outp, (void*)&barB, (void*)&preB, (void*)&rev};
        (void)hipLaunchCooperativeKernel((const void*)gru_scan14, dim3(NWG), dim3(NTH),
                                         args, 0, stream);
    }
}

// Round 16
// 6463.020 us; speedup vs baseline: 1.1799x; 1.1799x over previous
//
#include <hip/hip_runtime.h>
#include <math.h>

#define LSEQ 128
#define BATCH 64
#define EDIM 512
#define HDIM 1024
#define N3 3072
#define NWG 256
#define NTH 1024
#define GXT ((size_t)(N3 * BATCH))   // floats per time step in gxT ([3072][64])
#define BARSTRIDE 768                // ints per barrier instance

typedef float v4f __attribute__((ext_vector_type(4)));

// ---------------------------------------------------------------------------
// agent-scope (IF-serviced, cross-XCD coherent) 16B accesses
// ---------------------------------------------------------------------------
__device__ __forceinline__ v4f sc1Ld4(const float* p) {
    v4f v;
    asm volatile("global_load_dwordx4 %0, %1, off sc1"
                 : "=v"(v) : "v"(p) : "memory");
    return v;
}
__device__ __forceinline__ void sc1St4(float* p, v4f v) {
    asm volatile("global_store_dwordx4 %0, %1, off sc1"
                 : : "v"(p), "v"(v) : "memory");
}

// ---------------------------------------------------------------------------
// XCD-local atomic (serviced at the issuing XCD's L2; no sc1 -> not IF-routed).
// Atomics always execute at L2 (never satisfied from L1), so add-0 is a safe
// L2-visible read. sc0 = return-old.
// ---------------------------------------------------------------------------
__device__ __forceinline__ int l2AtomicAdd(int* p, int v) {
    int old;
    asm volatile("global_atomic_add %0, %1, %2, off sc0\n\ts_waitcnt vmcnt(0)"
                 : "=v"(old) : "v"(p), "v"(v) : "memory");
    return old;
}
__device__ __forceinline__ int xccId() {
    int x;
    asm("s_getreg_b32 %0, hwreg(HW_REG_XCC_ID)" : "=s"(x));
    return x & 7;
}

// ---------------------------------------------------------------------------
// Hierarchical grid barrier (deadlock-proof form). Instance layout (ints,
// pre-zeroed, fresh per use; all hot slots 128B apart):
//   arr[x]  at x*32       local arrival counters (one per XCD)
//   root    at 256        agent-scope root counter
//   rootrel at 288        agent-scope root release flag
//   rel[x]  at (16+x)*32  local release counters
// Arrivals are LOCAL atomics (parallel across 8 L2s); only the last WG per
// XCD touches agent scope (1 RMW + poll); local pollers use atomic add-0
// (L2-executed, can't be L1-stale) with an agent-scope fallback check every
// 64 sleeps (rootrel==1 already implies all arrivals -> safe to proceed).
// ---------------------------------------------------------------------------
__device__ __forceinline__ void xcd_bar(int* base, int myx, int cntx, int nxcd) {
    __syncthreads();   // compiler drains each wave's vmem before s_barrier
    if (threadIdx.x == 0) {
        asm volatile("s_waitcnt vmcnt(0)" ::: "memory");
        const int old = l2AtomicAdd(&base[myx * 32], 1);
        if (old == cntx - 1) {      // last arriver on this XCD
            const int rold = __hip_atomic_fetch_add(&base[256], 1,
                                 __ATOMIC_RELAXED, __HIP_MEMORY_SCOPE_AGENT);
            if (rold == nxcd - 1)
                __hip_atomic_store(&base[288], 1, __ATOMIC_RELAXED,
                                   __HIP_MEMORY_SCOPE_AGENT);
            while (__hip_atomic_load(&base[288], __ATOMIC_RELAXED,
                                     __HIP_MEMORY_SCOPE_AGENT) == 0)
                __builtin_amdgcn_s_sleep(2);
            l2AtomicAdd(&base[(16 + myx) * 32], 1);   // local release
        } else {
            int it = 0;
            while (l2AtomicAdd(&base[(16 + myx) * 32], 0) == 0) {
                __builtin_amdgcn_s_sleep(2);
                if ((++it & 63) == 0) {
                    if (__hip_atomic_load(&base[288], __ATOMIC_RELAXED,
                                          __HIP_MEMORY_SCOPE_AGENT) != 0)
                        break;   // agent fallback: release already implied
                }
            }
        }
    }
    __syncthreads();
}

// ---------------------------------------------------------------------------
// f32 tiled GEMM, optional row-gather on A. Output BLOCK-TRANSPOSED to gxT.
// ---------------------------------------------------------------------------
__global__ __launch_bounds__(256) void gemm_biasT(
    const float* __restrict__ A, const int* __restrict__ idx, int K,
    const float* __restrict__ Bm, const float* __restrict__ bias,
    float* __restrict__ C, int N)
{
    __shared__ float Sm[4352];
    float* As = Sm;
    float* Bs = Sm + 2176;
    const int tid = threadIdx.x;
    const int m0 = blockIdx.y * 64, n0 = blockIdx.x * 64;
    const int ty = tid >> 4, tx = tid & 15;

    float acc[4][4] = {};

    const int ra = tid >> 3;
    const int kq = (tid & 7) << 2;
    const int kb = tid >> 4;
    const int nq = (tid & 15) << 2;

    for (int k0 = 0; k0 < K; k0 += 32) {
        #pragma unroll
        for (int h2 = 0; h2 < 2; ++h2) {
            const int row = ra + h2 * 32;
            const int grow = idx ? idx[m0 + row] : (m0 + row);
            const float4 v = *reinterpret_cast<const float4*>(&A[(size_t)grow * K + k0 + kq]);
            As[(kq + 0) * 68 + row] = v.x; As[(kq + 1) * 68 + row] = v.y;
            As[(kq + 2) * 68 + row] = v.z; As[(kq + 3) * 68 + row] = v.w;
        }
        #pragma unroll
        for (int h2 = 0; h2 < 2; ++h2) {
            const int kk = kb + h2 * 16;
            *reinterpret_cast<float4*>(&Bs[kk * 68 + nq]) =
                *reinterpret_cast<const float4*>(&Bm[(size_t)(k0 + kk) * N + n0 + nq]);
        }
        __syncthreads();
        #pragma unroll
        for (int k = 0; k < 32; ++k) {
            const float4 a4 = *reinterpret_cast<const float4*>(&As[k * 68 + ty * 4]);
            const float4 b4 = *reinterpret_cast<const float4*>(&Bs[k * 68 + tx * 4]);
            const float av[4] = {a4.x, a4.y, a4.z, a4.w};
            const float bv[4] = {b4.x, b4.y, b4.z, b4.w};
            #pragma unroll
            for (int i = 0; i < 4; ++i)
                #pragma unroll
                for (int j = 0; j < 4; ++j)
                    acc[i][j] += av[i] * bv[j];
        }
        __syncthreads();
    }

    #pragma unroll
    for (int i = 0; i < 4; ++i) {
        float4 v = {acc[i][0] + bias[n0 + tx * 4 + 0],
                    acc[i][1] + bias[n0 + tx * 4 + 1],
                    acc[i][2] + bias[n0 + tx * 4 + 2],
                    acc[i][3] + bias[n0 + tx * 4 + 3]};
        *reinterpret_cast<float4*>(&Sm[(ty * 4 + i) * 65 + tx * 4]) = v;
    }
    __syncthreads();
    const int mloc = tid & 63, nq2 = tid >> 6;
    const size_t base = (size_t)blockIdx.y * ((size_t)N * 64) + (size_t)n0 * 64;
    #pragma unroll
    for (int q = 0; q < 16; ++q) {
        const int nl = nq2 * 16 + q;
        C[base + (size_t)nl * 64 + mloc] = Sm[mloc * 65 + nl];
    }
}

// ---------------------------------------------------------------------------
// GRU scan v11 (proven best: 2.89 ms/scan) — v7 data plane,
// XCD-hierarchical barriers. Zone-overlay invariants (unchanged since v6):
//   h(t)  -> zone(u)[c][b], rh(t) -> zone(u)[1024+c][b], u = t-1 fwd / t+1 bwd
//   zone(x) = gxT + x*GXT for 0<=x<L else scr (per-direction).
// Gate z/r regions only ever read via sc1 (no L2 allocation on any XCD) so
// overlay writes can't be shadowed; overlay data plain-read only at fresh
// addresses after a barrier; cand region never overlaid.
// pre arena (pre-zeroed): [0] census counter, [16..23] per-XCD WG counts.
// ---------------------------------------------------------------------------
__global__ __launch_bounds__(NTH) void gru_scan11(
    float* __restrict__ gxT,
    float* __restrict__ scr,
    const float* __restrict__ Whzr,   // [1024][2048]
    const float* __restrict__ bhzr,
    const float* __restrict__ Whh,    // [1024][1024]
    const float* __restrict__ bhh,
    const float* __restrict__ mask,   // [L][B]
    float* __restrict__ out,          // [L][B][1024]
    int* __restrict__ bar,            // [2*LSEQ][BARSTRIDE] pre-zeroed
    int* __restrict__ pre,            // [32] pre-zeroed census arena
    int reverse)
{
    __shared__ float Wzr_l[HDIM * 16];   // [k][8z|8r]  64KB
    __shared__ float Whh_l[HDIM * 8];    // [k][8c]     32KB
    __shared__ float part[8192];         // 32KB reduce scratch
    __shared__ float gl[512];            // [16 gate cols][32b]
    __shared__ float candl[256];         // [8c][32b]
    __shared__ float zl[256];            // [8c][32b]
    __shared__ float hold[256];          // [8c][32b]
    __shared__ float rhl[256];           // [8c][32b]
    __shared__ float hl[256];            // [8c][32b]
    __shared__ float ml[32];

    const int wg = blockIdx.x, tid = threadIdx.x;
    const int w = tid >> 6, lane = tid & 63;
    const int bq = lane & 7, gp = lane >> 3;
    const int c0 = (wg >> 1) * 8;
    const int grp = wg & 1;
    const int b0 = grp * 32;

    const int myx = xccId();

    // ---- census: per-XCD membership counts (once, agent-scope) ----
    if (tid == 0)
        __hip_atomic_fetch_add(&pre[16 + myx], 1,
                               __ATOMIC_RELAXED, __HIP_MEMORY_SCOPE_AGENT);

    // one-time weight staging (k = tid)
    {
        const int k = tid;
        *(v4f*)&Wzr_l[k * 16]      = *(const v4f*)&Whzr[(size_t)k * 2048 + c0];
        *(v4f*)&Wzr_l[k * 16 + 4]  = *(const v4f*)&Whzr[(size_t)k * 2048 + c0 + 4];
        *(v4f*)&Wzr_l[k * 16 + 8]  = *(const v4f*)&Whzr[(size_t)k * 2048 + 1024 + c0];
        *(v4f*)&Wzr_l[k * 16 + 12] = *(const v4f*)&Whzr[(size_t)k * 2048 + 1024 + c0 + 4];
        *(v4f*)&Whh_l[k * 8]       = *(const v4f*)&Whh[(size_t)k * 1024 + c0];
        *(v4f*)&Whh_l[k * 8 + 4]   = *(const v4f*)&Whh[(size_t)k * 1024 + c0 + 4];
    }

    // ---- census barrier (flat agent, once) + count readback (leader) ----
    int cntx = NWG, nxcd = 1;
    __syncthreads();
    if (tid == 0) {
        asm volatile("s_waitcnt vmcnt(0)" ::: "memory");
        __hip_atomic_fetch_add(&pre[0], 1, __ATOMIC_RELAXED,
                               __HIP_MEMORY_SCOPE_AGENT);
        while (__hip_atomic_load(&pre[0], __ATOMIC_RELAXED,
                                 __HIP_MEMORY_SCOPE_AGENT) < NWG)
            __builtin_amdgcn_s_sleep(2);
        nxcd = 0;
        for (int x2 = 0; x2 < 8; ++x2) {
            const int c = __hip_atomic_load(&pre[16 + x2], __ATOMIC_RELAXED,
                                            __HIP_MEMORY_SCOPE_AGENT);
            if (x2 == myx) cntx = c;
            if (c > 0) ++nxcd;
        }
    }
    __syncthreads();

    // reduce-A mapping (tid < 512): output (gate gcA, batch bA)
    const int remA = tid & 255;
    const int lqA = remA >> 2, eA = remA & 3;
    const int bA  = (lqA & 7) * 4 + ((tid >> 8) & 1) * 2 + (eA >> 1);
    const int gcA = (lqA >> 3) * 2 + (eA & 1);
    const int colA = (gcA < 8) ? (c0 + gcA) : (1024 + c0 + gcA - 8);
    const float bzrA = bhzr[colA & 2047];
    const int jA = gcA - 8;
    // reduce-B mapping (tid < 256): output (col cB, batch bB)
    const int lqB = tid >> 2, eB = tid & 3;
    const int bB = (lqB & 7) * 4 + eB;
    const int cB = lqB >> 3;
    const float bhhB = (tid < 256) ? bhh[c0 + cB] : 0.f;

    for (int s = 0; s < LSEQ; ++s) {
        const int t  = reverse ? (LSEQ - 1 - s) : s;
        const int u  = reverse ? (t + 1) : (t - 1);
        const int up = reverse ? (t + 2) : (t - 2);
        float* zoneU = (u >= 0 && u < LSEQ) ? (gxT + (size_t)u * GXT) : scr;
        const float* zoneP = (up >= 0 && up < LSEQ) ? (gxT + (size_t)up * GXT) : scr;
        int* barA = bar + (size_t)(2 * s) * BARSTRIDE;
        int* barB = bar + (size_t)(2 * s + 1) * BARSTRIDE;

        // ================= prefetch block (wave-role parallel) =================
        v4f gv = {0,0,0,0};
        float4 hv = {0,0,0,0}, cv = {0,0,0,0}, mv = {0,0,0,0};
        if (tid < 128) {                 // waves 0-1: z/r gates via sc1 x4
            const int ci = tid >> 3, qq = tid & 7;
            const int col = (ci < 8) ? (c0 + ci) : (1024 + c0 + ci - 8);
            gv = sc1Ld4(&gxT[(size_t)t * GXT + (size_t)col * 64 + b0 + qq * 4]);
        } else if (tid < 192) {          // wave 2: h_old own cols (plain, fresh)
            if (s > 0) {
                const int ci = (tid - 128) >> 3, qq = tid & 7;
                hv = *(const float4*)&zoneP[(size_t)(c0 + ci) * 64 + b0 + qq * 4];
            }
        } else if (tid < 256) {          // wave 3: cand gates (plain, never overlaid)
            const int ci = (tid - 192) >> 3, qq = tid & 7;
            cv = *(const float4*)&gxT[(size_t)t * GXT + (size_t)(2048 + c0 + ci) * 64 + b0 + qq * 4];
        } else if (tid < 264) {          // wave 4 lanes 0-7: mask
            const int qq = tid - 256;
            mv = *(const float4*)&mask[t * BATCH + b0 + qq * 4];
        }
        asm volatile("s_waitcnt vmcnt(0)" ::: "memory");
        __builtin_amdgcn_sched_barrier(0);
        if (tid < 128) {
            *(v4f*)&gl[(tid >> 3) * 32 + (tid & 7) * 4] = gv;
        } else if (tid < 192) {
            *(float4*)&hold[((tid - 128) >> 3) * 32 + (tid & 7) * 4] = hv;
        } else if (tid < 256) {
            *(float4*)&candl[((tid - 192) >> 3) * 32 + (tid & 7) * 4] = cv;
        } else if (tid < 264) {
            *(float4*)&ml[(tid - 256) * 4] = mv;
        }
        __syncthreads();

        // ---- phase A GEMM: z,r partials; wave w owns K-slice [64w, 64w+64) ----
        float2 a00 = {0,0}, a01 = {0,0}, a10 = {0,0}, a11 = {0,0};
        if (s > 0) {
            const float* hb = zoneP + (size_t)(w * 64) * 64 + b0 + bq * 4;
            const float* wb = &Wzr_l[(w * 64) * 16 + gp * 2];
            #pragma unroll 8
            for (int kk = 0; kk < 64; ++kk) {
                const float4 h4 = *(const float4*)(hb + (size_t)kk * 64);
                const float2 w2 = *(const float2*)(wb + kk * 16);
                a00.x += h4.x * w2.x; a00.y += h4.y * w2.x;
                a01.x += h4.z * w2.x; a01.y += h4.w * w2.x;
                a10.x += h4.x * w2.y; a10.y += h4.y * w2.y;
                a11.x += h4.z * w2.y; a11.y += h4.w * w2.y;
            }
        }
        {
            const float4 p0 = {a00.x, a10.x, a00.y, a10.y};
            const float4 p1 = {a01.x, a11.x, a01.y, a11.y};
            *(float4*)&part[w * 512 + lane * 4]       = p0;
            *(float4*)&part[w * 512 + 256 + lane * 4] = p1;
        }
        __syncthreads();
        if (tid < 512) {
            float sum = 0.f;
            #pragma unroll
            for (int ww = 0; ww < 16; ++ww) sum += part[ww * 512 + tid];
            const float pre_ = sum + bzrA + gl[gcA * 32 + bA];
            const float sig = 1.f / (1.f + expf(-pre_));
            if (gcA < 8) zl[gcA * 32 + bA] = sig;
            else         rhl[jA * 32 + bA] = sig * hold[jA * 32 + bA];
        }
        __syncthreads();
        if (tid < 64) {                  // 64 x4 sc1 stores: rh -> zoneU r-region
            const int ci = tid >> 3, qq = tid & 7;
            sc1St4(&zoneU[(size_t)(1024 + c0 + ci) * 64 + b0 + qq * 4],
                   *(const v4f*)&rhl[ci * 32 + qq * 4]);
        }
        xcd_bar(barA, myx, cntx, nxcd);

        // ---- phase B GEMM: candidate partials over rh (plain b128, fresh) ----
        float2 q01 = {0,0}, q23 = {0,0};
        if (s > 0) {
            const float* rb  = zoneU + (size_t)(1024 + w * 64) * 64 + b0 + bq * 4;
            const float* wb2 = &Whh_l[(w * 64) * 8 + gp];
            #pragma unroll 8
            for (int kk = 0; kk < 64; ++kk) {
                const float4 r4 = *(const float4*)(rb + (size_t)kk * 64);
                const float wv = wb2[kk * 8];
                q01.x += r4.x * wv; q01.y += r4.y * wv;
                q23.x += r4.z * wv; q23.y += r4.w * wv;
            }
        }
        {
            const float4 pv = {q01.x, q01.y, q23.x, q23.y};
            *(float4*)&part[w * 256 + lane * 4] = pv;
        }
        __syncthreads();
        if (tid < 256) {
            float sum = 0.f;
            #pragma unroll
            for (int ww = 0; ww < 16; ++ww) sum += part[ww * 256 + tid];
            const float pre_ = sum + bhhB + candl[cB * 32 + bB];
            const float hc = tanhf(pre_);
            const float z  = zl[cB * 32 + bB];
            const float ho = hold[cB * 32 + bB];
            float hn = ho + z * (hc - ho);
            hn = ho + ml[bB] * (hn - ho);
            hl[cB * 32 + bB] = hn;
        }
        __syncthreads();
        if (tid < 64) {                  // 64 x4 sc1 stores: h -> zoneU z-region
            const int ci = tid >> 3, qq = tid & 7;
            sc1St4(&zoneU[(size_t)(c0 + ci) * 64 + b0 + qq * 4],
                   *(const v4f*)&hl[ci * 32 + qq * 4]);
        } else if (tid < 128) {          // out[t][b][c0..c0+8) plain x4 stores
            const int e = tid - 64;
            const int b = e >> 1, half = e & 1;
            float4 v;
            v.x = hl[(half * 4 + 0) * 32 + b];
            v.y = hl[(half * 4 + 1) * 32 + b];
            v.z = hl[(half * 4 + 2) * 32 + b];
            v.w = hl[(half * 4 + 3) * 32 + b];
            *(float4*)&out[((size_t)t * BATCH + b0 + b) * HDIM + c0 + half * 4] = v;
        }
        xcd_bar(barB, myx, cntx, nxcd);
    }
}

// ---------------------------------------------------------------------------
extern "C" void kernel_launch(void* const* d_in, const int* in_sizes, int n_in,
                              void* d_out, int out_size, void* d_ws, size_t ws_size,
                              hipStream_t stream) {
    const int*   xs      = (const int*)  d_in[0];
    const float* xs_mask = (const float*)d_in[1];
    const float* emb     = (const float*)d_in[2];
    const float* fw_Wx   = (const float*)d_in[3];
    const float* fw_bx   = (const float*)d_in[4];
    const float* fw_Whzr = (const float*)d_in[5];
    const float* fw_bhzr = (const float*)d_in[6];
    const float* fw_Whh  = (const float*)d_in[7];
    const float* fw_bhh  = (const float*)d_in[8];
    const float* bw_Wx   = (const float*)d_in[9];
    const float* bw_bx   = (const float*)d_in[10];
    const float* bw_Whzr = (const float*)d_in[11];
    const float* bw_bhzr = (const float*)d_in[12];
    const float* bw_Whh  = (const float*)d_in[13];
    const float* bw_bhh  = (const float*)d_in[14];
    float* outp = (float*)d_out;

    // bars: [2*LSEQ][BARSTRIDE] per direction; pre: 32 ints each direction
    const size_t BARN = (size_t)(2 * LSEQ) * BARSTRIDE;

    char* wp = (char*)d_ws;
    float* gxbuf = (float*)wp; wp += (size_t)LSEQ * GXT * sizeof(float);   // 100.7 MB
    float* scrF  = (float*)wp; wp += GXT * sizeof(float);
    float* scrB  = (float*)wp; wp += GXT * sizeof(float);
    int* barF    = (int*)wp;   wp += BARN * sizeof(int);
    int* barB    = (int*)wp;   wp += BARN * sizeof(int);
    int* preF    = (int*)wp;   wp += 32 * sizeof(int);
    int* preB    = (int*)wp;   wp += 32 * sizeof(int);

    hipMemsetAsync(barF, 0, (2 * BARN + 64) * sizeof(int), stream);

    const dim3 gemm_grid(N3 / 64, (LSEQ * BATCH) / 64);
    const dim3 gemm_blk(256);

    // ---- forward: gxT = (emb[xs] @ fw_Wx + fw_bx)^T-per-step ; scan ----
    hipLaunchKernelGGL(gemm_biasT, gemm_grid, gemm_blk, 0, stream,
                       emb, xs, EDIM, fw_Wx, fw_bx, gxbuf, N3);
    {
        int rev = 0;
        void* args[] = {(void*)&gxbuf, (void*)&scrF, (void*)&fw_Whzr, (void*)&fw_bhzr,
                        (void*)&fw_Whh, (void*)&fw_bhh, (void*)&xs_mask,
                        (void*)&outp, (void*)&barF, (void*)&preF, (void*)&rev};
        (void)hipLaunchCooperativeKernel((const void*)gru_scan11, dim3(NWG), dim3(NTH),
                                         args, 0, stream);
    }

    // ---- backward: gxT = (right @ bw_Wx + bw_bx)^T-per-step ; scan ----
    {
        const float* rightp = (const float*)d_out;
        const int* noidx = nullptr;
        hipLaunchKernelGGL(gemm_biasT, gemm_grid, gemm_blk, 0, stream,
                           rightp, noidx, HDIM, bw_Wx, bw_bx, gxbuf, N3);
    }
    {
        int rev = 1;
        void* args[] = {(void*)&gxbuf, (void*)&scrB, (void*)&bw_Whzr, (void*)&bw_bhzr,
                        (void*)&bw_Whh, (void*)&bw_bhh, (void*)&xs_mask,
                        (void*)&outp, (void*)&barB, (void*)&preB, (void*)&rev};
        (void)hipLaunchCooperativeKernel((const void*)gru_scan11, dim3(NWG), dim3(NTH),
                                         args, 0, stream);
    }
}